// Round 1
// baseline (636.557 us; speedup 1.0000x reference)
//
#include <hip/hip_runtime.h>
#include <cstdint>
#include <cstddef>

#define T_TOK 64
#define K_IN 4096
#define N_OUT 14336
#define KSTEPS (K_IN / 32)   // 128 MFMA k-steps

typedef __attribute__((ext_vector_type(8))) short bf16x8;
typedef __attribute__((ext_vector_type(4))) float f32x4;

static __device__ __forceinline__ unsigned short bf16_rne(float f) {
    unsigned u = __builtin_bit_cast(unsigned, f);
    unsigned r = (u + 0x7fffu + ((u >> 16) & 1u)) >> 16;
    return (unsigned short)r;
}

// Kernel 1: x (fp32) -> bf16 copy in ws, plus per-token row sums for the
// rank-1 correction term. 64 blocks (one per token row) x 256 threads.
__global__ __launch_bounds__(256) void prep_kernel(const float* __restrict__ x,
                                                   unsigned short* __restrict__ xbf,
                                                   float* __restrict__ rowsum) {
    const int row = blockIdx.x;
    const int t = threadIdx.x;
    const float4* x4 = (const float4*)(x + (size_t)row * K_IN);
    float s = 0.f;
#pragma unroll
    for (int i = 0; i < 4; i++) {
        float4 v = x4[i * 256 + t];
        s += v.x + v.y + v.z + v.w;
        ushort4 h;
        h.x = bf16_rne(v.x); h.y = bf16_rne(v.y);
        h.z = bf16_rne(v.z); h.w = bf16_rne(v.w);
        *(ushort4*)(xbf + (size_t)row * K_IN + (size_t)(i * 256 + t) * 4) = h;
    }
#pragma unroll
    for (int off = 32; off > 0; off >>= 1) s += __shfl_down(s, off, 64);
    __shared__ float part[4];
    const int wave = t >> 6, lane = t & 63;
    if (lane == 0) part[wave] = s;
    __syncthreads();
    if (t == 0) rowsum[row] = part[0] + part[1] + part[2] + part[3];
}

// Kernel 2: streaming int4-dequant GEMM.
// Grid: N_OUT/64 = 224 blocks x 256 threads (4 waves).
// Wave w owns columns blk*64 + w*16 + r (r = lane&15) and ALL 64 token rows
// via 4 mfma_f32_16x16x32_bf16 accumulators (M-tiles of 16).
// B: direct global->reg int32 loads of this lane's column (nontemporal,
//    k-strided; 4x64B segments per instruction, every byte used once).
// A: bf16 x from ws (L2-hot), 16B/lane fully coalesced.
// Register double-buffer prefetch; no LDS, no barriers in the K-loop.
__global__ __launch_bounds__(256) void gemm_kernel(const unsigned short* __restrict__ xbf,
                                                   const float* __restrict__ rowsum,
                                                   const int* __restrict__ W,
                                                   const float* __restrict__ scales,
                                                   const float* __restrict__ u,
                                                   const float* __restrict__ bias,
                                                   float* __restrict__ out) {
    const int tid = threadIdx.x;
    const int wave = tid >> 6;
    const int lane = tid & 63;
    const int q = lane >> 4;       // quad: k-offset q*8 in A/B frags
    const int r = lane & 15;       // column within wave's 16-col strip
    const int col = blockIdx.x * 64 + wave * 16 + r;

    const int* __restrict__ wcol = W + col;            // stride N_OUT per k
    const float* __restrict__ scol = scales + col;     // stride N_OUT per group
    const unsigned short* __restrict__ xr = xbf + (size_t)r * K_IN;

    f32x4 acc[4];
#pragma unroll
    for (int mt = 0; mt < 4; mt++) acc[mt] = f32x4{0.f, 0.f, 0.f, 0.f};

    int4 abuf[2][4];
    int bbuf[2][8];
    float sbuf[2];

    // prologue: load step 0
    {
        const int base = q * 8;
        sbuf[0] = scol[0];
#pragma unroll
        for (int j = 0; j < 8; j++)
            bbuf[0][j] = __builtin_nontemporal_load(wcol + (size_t)(base + j) * N_OUT);
#pragma unroll
        for (int mt = 0; mt < 4; mt++)
            abuf[0][mt] = *(const int4*)(xr + (size_t)mt * 16 * K_IN + base);
    }

    for (int ks = 0; ks < KSTEPS; ks++) {
        const int cur = ks & 1;
        if (ks + 1 < KSTEPS) {
            const int nxt = cur ^ 1;
            const int base = (ks + 1) * 32 + q * 8;
            // scale first so its vmcnt slot precedes the bulk prefetch
            sbuf[nxt] = scol[(size_t)((ks + 1) >> 2) * N_OUT];
#pragma unroll
            for (int j = 0; j < 8; j++)
                bbuf[nxt][j] = __builtin_nontemporal_load(wcol + (size_t)(base + j) * N_OUT);
#pragma unroll
            for (int mt = 0; mt < 4; mt++)
                abuf[nxt][mt] = *(const int4*)(xr + (size_t)mt * 16 * K_IN + base);
        }

        // dequant current B ints -> bf16 fragment (RNE)
        const float sc = sbuf[cur];
        bf16x8 bf;
#pragma unroll
        for (int j = 0; j < 8; j++)
            bf[j] = (short)bf16_rne((float)bbuf[cur][j] * sc);

#pragma unroll
        for (int mt = 0; mt < 4; mt++)
            acc[mt] = __builtin_amdgcn_mfma_f32_16x16x32_bf16(
                __builtin_bit_cast(bf16x8, abuf[cur][mt]), bf, acc[mt], 0, 0, 0);
    }

    // epilogue: + bias + rowsum * u   (C/D layout: row = q*4 + i, col = r)
    const float bcol = bias[col];
    const float ucol = u[col];
#pragma unroll
    for (int mt = 0; mt < 4; mt++) {
#pragma unroll
        for (int i = 0; i < 4; i++) {
            const int t = mt * 16 + q * 4 + i;
            out[(size_t)t * N_OUT + col] = acc[mt][i] + bcol + rowsum[t] * ucol;
        }
    }
}

extern "C" void kernel_launch(void* const* d_in, const int* in_sizes, int n_in,
                              void* d_out, int out_size, void* d_ws, size_t ws_size,
                              hipStream_t stream) {
    const float* x      = (const float*)d_in[0];
    const int*   W      = (const int*)d_in[1];
    const float* scales = (const float*)d_in[2];
    const float* u      = (const float*)d_in[3];
    const float* bias   = (const float*)d_in[4];
    float* out = (float*)d_out;

    unsigned short* xbf = (unsigned short*)d_ws;                        // 64*4096*2 = 512 KB
    float* rowsum = (float*)((char*)d_ws + (size_t)T_TOK * K_IN * 2);   // 64 floats

    prep_kernel<<<T_TOK, 256, 0, stream>>>(x, xbf, rowsum);
    gemm_kernel<<<N_OUT / 64, 256, 0, stream>>>(xbf, rowsum, W, scales, u, bias, out);
}

// Round 4
// 371.873 us; speedup vs baseline: 1.7118x; 1.7118x over previous
//
#include <hip/hip_runtime.h>
#include <cstdint>
#include <cstddef>

#define T_TOK 64
#define K_IN 4096
#define N_OUT 14336
#define SPLITK 8
#define KCHUNK (K_IN / SPLITK)        // 512 k per block
#define KSTEPS (KCHUNK / 32)          // 16 MFMA k-steps per block

typedef __attribute__((ext_vector_type(8))) short bf16x8;
typedef __attribute__((ext_vector_type(4))) float f32x4;

static __device__ __forceinline__ unsigned short bf16_rne(float f) {
    unsigned u = __builtin_bit_cast(unsigned, f);
    unsigned r = (u + 0x7fffu + ((u >> 16) & 1u)) >> 16;
    return (unsigned short)r;
}

// Kernel 1: x (fp32) -> bf16 copy in ws + per-token row sums.
__global__ __launch_bounds__(256) void prep_kernel(const float* __restrict__ x,
                                                   unsigned short* __restrict__ xbf,
                                                   float* __restrict__ rowsum) {
    const int row = blockIdx.x;
    const int t = threadIdx.x;
    const float4* x4 = (const float4*)(x + (size_t)row * K_IN);
    float s = 0.f;
#pragma unroll
    for (int i = 0; i < 4; i++) {
        float4 v = x4[i * 256 + t];
        s += v.x + v.y + v.z + v.w;
        ushort4 h;
        h.x = bf16_rne(v.x); h.y = bf16_rne(v.y);
        h.z = bf16_rne(v.z); h.w = bf16_rne(v.w);
        *(ushort4*)(xbf + (size_t)row * K_IN + (size_t)(i * 256 + t) * 4) = h;
    }
#pragma unroll
    for (int off = 32; off > 0; off >>= 1) s += __shfl_down(s, off, 64);
    __shared__ float part[4];
    const int wave = t >> 6, lane = t & 63;
    if (lane == 0) part[wave] = s;
    __syncthreads();
    if (t == 0) rowsum[row] = part[0] + part[1] + part[2] + part[3];
}

// Kernel 2: initialize out with bias + rowsum*u (the split-K partials are
// atomically accumulated on top). Grid (N_OUT/4/256, T_TOK).
__global__ __launch_bounds__(256) void init_kernel(const float* __restrict__ rowsum,
                                                   const float* __restrict__ u,
                                                   const float* __restrict__ bias,
                                                   float* __restrict__ out) {
    const int t = blockIdx.y;
    const int n4 = blockIdx.x * 256 + threadIdx.x;      // float4 index within row
    const float rs = rowsum[t];
    float4 b = ((const float4*)bias)[n4];
    float4 uu = ((const float4*)u)[n4];
    float4 o;
    o.x = b.x + rs * uu.x; o.y = b.y + rs * uu.y;
    o.z = b.z + rs * uu.z; o.w = b.w + rs * uu.w;
    ((float4*)(out + (size_t)t * N_OUT))[n4] = o;
}

// Kernel 3: split-K streaming int4-dequant GEMM.
// Grid: (N_OUT/64, SPLITK) = (224, 8) = 1792 blocks x 256 threads (4 waves).
// Wave w owns columns blk.x*64 + w*16 + r and all 64 token rows over a
// 512-deep K chunk; partials atomicAdd'ed into pre-initialized out.
__global__ __launch_bounds__(256, 4) void gemm_kernel(const unsigned short* __restrict__ xbf,
                                                      const int* __restrict__ W,
                                                      const float* __restrict__ scales,
                                                      float* __restrict__ out) {
    const int tid = threadIdx.x;
    const int wave = tid >> 6;
    const int lane = tid & 63;
    const int q = lane >> 4;       // quad: k-offset q*8 in A/B frags
    const int r = lane & 15;       // column within wave's 16-col strip
    const int col = blockIdx.x * 64 + wave * 16 + r;
    const int kbase = blockIdx.y * KCHUNK;
    const int gbase = kbase / 128;                     // first scale group

    const int* __restrict__ wcol = W + (size_t)kbase * N_OUT + col;   // stride N_OUT per k
    const float* __restrict__ scol = scales + (size_t)gbase * N_OUT + col;
    const unsigned short* __restrict__ xr = xbf + (size_t)r * K_IN + kbase;

    f32x4 acc[4];
#pragma unroll
    for (int mt = 0; mt < 4; mt++) acc[mt] = f32x4{0.f, 0.f, 0.f, 0.f};

    int4 abuf[2][4];
    int bbuf[2][8];
    float sbuf[2];

    // prologue: load step 0
    {
        const int base = q * 8;
        sbuf[0] = scol[0];
#pragma unroll
        for (int j = 0; j < 8; j++)
            bbuf[0][j] = wcol[(size_t)(base + j) * N_OUT];
#pragma unroll
        for (int mt = 0; mt < 4; mt++)
            abuf[0][mt] = *(const int4*)(xr + (size_t)mt * 16 * K_IN + base);
    }

    for (int ks = 0; ks < KSTEPS; ks++) {
        const int cur = ks & 1;
        if (ks + 1 < KSTEPS) {
            const int nxt = cur ^ 1;
            const int base = (ks + 1) * 32 + q * 8;
            sbuf[nxt] = scol[(size_t)((ks + 1) >> 2) * N_OUT];
#pragma unroll
            for (int j = 0; j < 8; j++)
                bbuf[nxt][j] = wcol[(size_t)(base + j) * N_OUT];
#pragma unroll
            for (int mt = 0; mt < 4; mt++)
                abuf[nxt][mt] = *(const int4*)(xr + (size_t)mt * 16 * K_IN + base);
        }

        // dequant current B ints -> bf16 fragment (RNE)
        const float sc = sbuf[cur];
        bf16x8 bf;
#pragma unroll
        for (int j = 0; j < 8; j++)
            bf[j] = (short)bf16_rne((float)bbuf[cur][j] * sc);

#pragma unroll
        for (int mt = 0; mt < 4; mt++)
            acc[mt] = __builtin_amdgcn_mfma_f32_16x16x32_bf16(
                __builtin_bit_cast(bf16x8, abuf[cur][mt]), bf, acc[mt], 0, 0, 0);
    }

    // epilogue: atomic accumulate partial tile (C/D layout: row = q*4+i, col = r)
#pragma unroll
    for (int mt = 0; mt < 4; mt++) {
#pragma unroll
        for (int i = 0; i < 4; i++) {
            const int t = mt * 16 + q * 4 + i;
            atomicAdd(out + (size_t)t * N_OUT + col, acc[mt][i]);
        }
    }
}

extern "C" void kernel_launch(void* const* d_in, const int* in_sizes, int n_in,
                              void* d_out, int out_size, void* d_ws, size_t ws_size,
                              hipStream_t stream) {
    const float* x      = (const float*)d_in[0];
    const int*   W      = (const int*)d_in[1];
    const float* scales = (const float*)d_in[2];
    const float* u      = (const float*)d_in[3];
    const float* bias   = (const float*)d_in[4];
    float* out = (float*)d_out;

    unsigned short* xbf = (unsigned short*)d_ws;                        // 64*4096*2 = 512 KB
    float* rowsum = (float*)((char*)d_ws + (size_t)T_TOK * K_IN * 2);   // 64 floats

    prep_kernel<<<T_TOK, 256, 0, stream>>>(x, xbf, rowsum);
    init_kernel<<<dim3(N_OUT / 4 / 256, T_TOK), 256, 0, stream>>>(rowsum, u, bias, out);
    gemm_kernel<<<dim3(N_OUT / 64, SPLITK), 256, 0, stream>>>(xbf, W, scales, out);
}